// Round 8
// baseline (246.178 us; speedup 1.0000x reference)
//
#include <hip/hip_runtime.h>
#include <hip/hip_bf16.h>
#include <math.h>

#define KNN 5
#define K3 27
#define CENTER 13
#define NCLASSES 21
#define DIM_D 32
#define DIM_H 128
#define DIM_W 2048

// full sort key (16 bits, z-major): z<<11 | y<<4 | x>>7
// LSD radix: digit0 = key & 0xFF (y-low:4, x>>7:4), digit1 = key >> 8 (z:5, y-high:3)
// payload w.y = x | y<<11 | z<<18 -> d0 = (w.y>>7)&0xFF, d1 = (w.y>>15)&0xFF
#define RADIX 256
#define BIN_PTS 2048
#define BIN_THREADS 256

__device__ __forceinline__ unsigned key16(int x, int y, int z) {
    return ((unsigned)z << 11) | ((unsigned)y << 4) | ((unsigned)x >> 7);
}

// ---------------- pass 0: global digit-0 histogram ----------------
__global__ __launch_bounds__(256) void hist0_kernel(
    const int* __restrict__ px, const int* __restrict__ py,
    unsigned* __restrict__ h0, int P)
{
    __shared__ unsigned lh0[RADIX];
    int t = threadIdx.x;
    lh0[t] = 0;
    __syncthreads();
    int base4 = blockIdx.x * 1024 + t;
#pragma unroll
    for (int g = 0; g < 4; ++g) {
        int i4 = base4 + g * 256;
        int i0 = i4 * 4;
        if (i0 + 3 < P) {
            int4 X = ((const int4*)px)[i4];
            int4 Y = ((const int4*)py)[i4];
            atomicAdd(&lh0[(((unsigned)Y.x & 0xF) << 4) | ((unsigned)X.x >> 7)], 1u);
            atomicAdd(&lh0[(((unsigned)Y.y & 0xF) << 4) | ((unsigned)X.y >> 7)], 1u);
            atomicAdd(&lh0[(((unsigned)Y.z & 0xF) << 4) | ((unsigned)X.z >> 7)], 1u);
            atomicAdd(&lh0[(((unsigned)Y.w & 0xF) << 4) | ((unsigned)X.w >> 7)], 1u);
        } else {
            for (int i = i0; i < P; ++i)
                atomicAdd(&lh0[(((unsigned)py[i] & 0xF) << 4) | ((unsigned)px[i] >> 7)], 1u);
        }
    }
    __syncthreads();
    if (lh0[t]) atomicAdd(&h0[t], lh0[t]);
}

// exclusive scan of one 256-entry array in place
__global__ __launch_bounds__(256) void scan256_kernel(unsigned* __restrict__ h)
{
    __shared__ unsigned ws[4];
    int t = threadIdx.x, lane = t & 63, wid = t >> 6;
    unsigned a = h[t], ia = a;
#pragma unroll
    for (int off = 1; off < 64; off <<= 1) {
        unsigned v = __shfl_up(ia, off);
        if (lane >= off) ia += v;
    }
    if (lane == 63) ws[wid] = ia;
    __syncthreads();
    unsigned b = 0;
#pragma unroll
    for (int w = 0; w < 4; ++w) b += (w < wid) ? ws[w] : 0u;
    h[t] = b + ia - a;
}

// ---------------- binning machinery ----------------
struct BinShared {
    unsigned lh[RADIX];
    unsigned lscan[RADIX];
    unsigned gbase[RADIX];
    unsigned wsum[4];
    uint4 stage[BIN_PTS];   // 32 KB
};

__device__ __forceinline__ void bin_local_scan(BinShared& S, int t)
{
    int lane = t & 63, wid = t >> 6;
    unsigned c = S.lh[t];
    unsigned inc = c;
#pragma unroll
    for (int off = 1; off < 64; off <<= 1) {
        unsigned v = __shfl_up(inc, off);
        if (lane >= off) inc += v;
    }
    if (lane == 63) S.wsum[wid] = inc;
    __syncthreads();
    unsigned wb = 0;
#pragma unroll
    for (int w = 0; w < 4; ++w) wb += (w < wid) ? S.wsum[w] : 0u;
    S.lscan[t] = wb + inc - c;
}

// pass 1: read original SoA arrays, bin by digit0 (cursor atomics on h0).
// FUSED: while writing outputs, accumulate the pass-2 per-block digit-1
// histogram M[d1][pos>>11] directly (replaces the hist_p2 dispatch).
__global__ __launch_bounds__(BIN_THREADS) void bin_pass1_kernel(
    const float* __restrict__ ur, const int* __restrict__ px,
    const int* __restrict__ py, const int* __restrict__ pz,
    unsigned* __restrict__ g0, uint4* __restrict__ outp,
    unsigned* __restrict__ M, int gridB, int P)
{
    __shared__ BinShared S;
    int t = threadIdx.x;
    int bstart = blockIdx.x * BIN_PTS;
    int n = min(BIN_PTS, P - bstart);
    S.lh[t] = 0;
    __syncthreads();

    uint4 pay[8];
    unsigned rk[8], dg[8];
#pragma unroll
    for (int g = 0; g < 2; ++g) {
        int i4 = (bstart >> 2) + g * 256 + t;
        int i0 = i4 * 4;
        if (i0 + 3 < P) {
            int4 X = ((const int4*)px)[i4];
            int4 Y = ((const int4*)py)[i4];
            int4 Z = ((const int4*)pz)[i4];
            float4 U = ((const float4*)ur)[i4];
            int xs[4] = {X.x, X.y, X.z, X.w};
            int ys[4] = {Y.x, Y.y, Y.z, Y.w};
            int zs[4] = {Z.x, Z.y, Z.z, Z.w};
            float us[4] = {U.x, U.y, U.z, U.w};
#pragma unroll
            for (int c = 0; c < 4; ++c) {
                int j = g * 4 + c;
                unsigned k = key16(xs[c], ys[c], zs[c]);
                dg[j] = k & 0xFFu;
                rk[j] = atomicAdd(&S.lh[dg[j]], 1u);
                pay[j] = make_uint4(__float_as_uint(us[c]),
                    (unsigned)xs[c] | ((unsigned)ys[c] << 11) | ((unsigned)zs[c] << 18),
                    (unsigned)(i0 + c), 0u);
            }
        } else {
#pragma unroll
            for (int c = 0; c < 4; ++c) {
                int j = g * 4 + c;
                int gi = i0 + c;
                if (gi < P) {
                    int x = px[gi], y = py[gi], z = pz[gi];
                    unsigned k = key16(x, y, z);
                    dg[j] = k & 0xFFu;
                    rk[j] = atomicAdd(&S.lh[dg[j]], 1u);
                    pay[j] = make_uint4(__float_as_uint(ur[gi]),
                        (unsigned)x | ((unsigned)y << 11) | ((unsigned)z << 18),
                        (unsigned)gi, 0u);
                } else {
                    dg[j] = 0xFFFFFFFFu;
                }
            }
        }
    }
    __syncthreads();
    bin_local_scan(S, t);
    S.gbase[t] = S.lh[t] ? atomicAdd(&g0[t], S.lh[t]) : 0u;
    __syncthreads();
#pragma unroll
    for (int j = 0; j < 8; ++j)
        if (dg[j] != 0xFFFFFFFFu)
            S.stage[S.lscan[dg[j]] + rk[j]] = pay[j];
    __syncthreads();
#pragma unroll
    for (int j = 0; j < 8; ++j) {
        int s = j * 256 + t;
        if (s < n) {
            uint4 v = S.stage[s];
            unsigned d = (v.y >> 7) & 0xFFu;
            unsigned pos = S.gbase[d] + ((unsigned)s - S.lscan[d]);
            outp[pos] = v;
            unsigned d1 = (v.y >> 15) & 0xFFu;
            atomicAdd(&M[d1 * (unsigned)gridB + (pos >> 11)], 1u);
        }
    }
}

// per-digit exclusive scan: block d scans row M[d][0..gridB), total -> T[d].
__global__ __launch_bounds__(1024) void scan_digit_kernel(
    unsigned* __restrict__ M, unsigned* __restrict__ T, int gridB)
{
    __shared__ unsigned wsum[16];
    unsigned* row = M + (size_t)blockIdx.x * (unsigned)gridB;
    int t = threadIdx.x, lane = t & 63, wid = t >> 6;
    int C = (gridB + 1023) / 1024;
    int lo = t * C, hi = min(lo + C, gridB);

    unsigned s = 0;
    for (int i = lo; i < hi; ++i) s += row[i];
    unsigned incl = s;
#pragma unroll
    for (int off = 1; off < 64; off <<= 1) {
        unsigned v = __shfl_up(incl, off);
        if (lane >= off) incl += v;
    }
    if (lane == 63) wsum[wid] = incl;
    __syncthreads();
    if (wid == 0 && lane < 16) {
        unsigned v = wsum[lane], iv = v;
#pragma unroll
        for (int off = 1; off < 16; off <<= 1) {
            unsigned u = __shfl_up(iv, off);
            if (lane >= off) iv += u;
        }
        wsum[lane] = iv - v;
    }
    __syncthreads();
    unsigned run = wsum[wid] + (incl - s);
    for (int i = lo; i < hi; ++i) {
        unsigned v = row[i];
        row[i] = run;
        run += v;
    }
    if (t == 1023) T[blockIdx.x] = run;
}

// pass 2 STABLE: deterministic base = T[d] (scanned) + M[d][block].
__global__ __launch_bounds__(BIN_THREADS) void bin_pass2_stable_kernel(
    const uint4* __restrict__ inp, const unsigned* __restrict__ M,
    const unsigned* __restrict__ T, uint4* __restrict__ outp,
    int gridB, int P)
{
    __shared__ BinShared S;
    int t = threadIdx.x;
    int bstart = blockIdx.x * BIN_PTS;
    int n = min(BIN_PTS, P - bstart);
    S.lh[t] = 0;
    __syncthreads();

    uint4 pay[8];
    unsigned rk[8], dg[8];
#pragma unroll
    for (int j = 0; j < 8; ++j) {
        int i = bstart + j * 256 + t;
        if (i < P) {
            uint4 v = inp[i];
            pay[j] = v;
            dg[j] = (v.y >> 15) & 0xFFu;
            rk[j] = atomicAdd(&S.lh[dg[j]], 1u);
        } else {
            dg[j] = 0xFFFFFFFFu;
        }
    }
    __syncthreads();
    bin_local_scan(S, t);
    S.gbase[t] = T[t] + M[(unsigned)t * (unsigned)gridB + blockIdx.x];
    __syncthreads();
#pragma unroll
    for (int j = 0; j < 8; ++j)
        if (dg[j] != 0xFFFFFFFFu)
            S.stage[S.lscan[dg[j]] + rk[j]] = pay[j];
    __syncthreads();
#pragma unroll
    for (int j = 0; j < 8; ++j) {
        int s = j * 256 + t;
        if (s < n) {
            uint4 v = S.stage[s];
            unsigned d = (v.y >> 15) & 0xFFu;
            unsigned pos = S.gbase[d] + ((unsigned)s - S.lscan[d]);
            outp[pos] = v;
        }
    }
}

// ---------------- KNN main kernel: 2 points/thread ----------------
__device__ __forceinline__ int swizzle_block(int b, int nb) {
    if ((nb & 7) == 0) {
        int per = nb >> 3;
        return (b & 7) * per + (b >> 3);
    }
    return b;
}

__global__ __launch_bounds__(256) void bev_knn_aos2_kernel(
    const float* __restrict__ pr, const int* __restrict__ pa,
    const uint4* __restrict__ payload, int* __restrict__ out, int P)
{
    int lb = swizzle_block(blockIdx.x, gridDim.x);
    int t = threadIdx.x;
    int idx[2] = { lb * 512 + t, lb * 512 + 256 + t };

    bool act[2];
    float u[2];
    int x[2], y[2], z[2], oidx[2];
#pragma unroll
    for (int q = 0; q < 2; ++q) {
        act[q] = idx[q] < P;
        uint4 w = payload[act[q] ? idx[q] : 0];
        u[q] = __uint_as_float(w.x);
        x[q] = (int)(w.y & 0x7FFu);
        y[q] = (int)((w.y >> 11) & 0x7Fu);
        z[q] = (int)((w.y >> 18) & 0x1Fu);
        oidx[q] = (int)w.z;
    }

    // gather 27 neighbor ranges for BOTH points (54 loads in flight)
    float dist[2][K3];
#pragma unroll
    for (int k = 0; k < K3; ++k) {
        const int dz = k / 9 - 1;
        const int dy = (k / 3) % 3 - 1;
        const int dx = k % 3 - 1;
#pragma unroll
        for (int q = 0; q < 2; ++q) {
            int zz = z[q] + dz, yy = y[q] + dy, xx = x[q] + dx;
            bool ok = ((unsigned)zz < (unsigned)DIM_D) &
                      ((unsigned)yy < (unsigned)DIM_H) &
                      ((unsigned)xx < (unsigned)DIM_W);
            int zi = ok ? zz : 0;
            int yi = ok ? yy : 0;
            int xi = ok ? xx : 0;
            float r = pr[((size_t)zi * DIM_H + yi) * DIM_W + xi];
            r = ok ? r : 0.0f;
            r = (r < 0.0f) ? INFINITY : r;
            float d = fabsf(r - u[q]);
            dist[q][k] = (k == CENTER) ? 0.0f : d;
        }
    }

    // top-5 smallest, ties -> lower flat index
    float bd[2][KNN];
    int   bk[2][KNN];
#pragma unroll
    for (int q = 0; q < 2; ++q) {
#pragma unroll
        for (int j = 0; j < KNN; ++j) { bd[q][j] = INFINITY; bk[q][j] = -1; }
#pragma unroll
        for (int k = 0; k < K3; ++k) {
            float dcur = dist[q][k];
            int   kcur = k;
#pragma unroll
            for (int j = 0; j < KNN; ++j) {
                bool take = dcur < bd[q][j];
                float td = bd[q][j]; int tk = bk[q][j];
                bd[q][j] = take ? dcur : bd[q][j];
                bk[q][j] = take ? kcur : bk[q][j];
                dcur = take ? td : dcur;
                kcur = take ? tk : kcur;
            }
        }
    }

    // class gather for the 10 winners + cutoff
    int votes[2][KNN];
#pragma unroll
    for (int j = 0; j < KNN; ++j) {
#pragma unroll
        for (int q = 0; q < 2; ++q) {
            int k = bk[q][j];
            const int dz = k / 9 - 1;
            const int dy = (k / 3) % 3 - 1;
            const int dx = k % 3 - 1;
            int zz = z[q] + dz, yy = y[q] + dy, xx = x[q] + dx;
            bool ok = ((unsigned)zz < (unsigned)DIM_D) &
                      ((unsigned)yy < (unsigned)DIM_H) &
                      ((unsigned)xx < (unsigned)DIM_W);
            int zi = ok ? zz : 0;
            int yi = ok ? yy : 0;
            int xi = ok ? xx : 0;
            int cls = pa[((size_t)zi * DIM_H + yi) * DIM_W + xi];
            cls = ok ? cls : 0;
            cls = (bd[q][j] > 1.0f) ? NCLASSES : cls;
            votes[q][j] = cls;
        }
    }

    // majority vote, ties -> lowest class
#pragma unroll
    for (int q = 0; q < 2; ++q) {
        int best_cnt = 0, best_cls = 1;
#pragma unroll
        for (int j = 0; j < KNN; ++j) {
            int v = votes[q][j];
            if (v >= 1 && v <= NCLASSES - 1) {
                int cnt = 0;
#pragma unroll
                for (int i = 0; i < KNN; ++i) cnt += (votes[q][i] == v) ? 1 : 0;
                if (cnt > best_cnt || (cnt == best_cnt && v < best_cls)) {
                    best_cnt = cnt;
                    best_cls = v;
                }
            }
        }
        if (act[q]) out[oidx[q]] = best_cls;
    }
}

// ---------------- direct fallback ----------------
__global__ __launch_bounds__(256) void bev_knn_direct_kernel(
    const float* __restrict__ pr, const int* __restrict__ pa,
    const float* __restrict__ ur, const int* __restrict__ px,
    const int* __restrict__ py, const int* __restrict__ pz,
    int* __restrict__ out, int P)
{
    int p = blockIdx.x * blockDim.x + threadIdx.x;
    if (p >= P) return;
    float u = ur[p];
    int x = px[p], y = py[p], z = pz[p];
    float dist[K3];
#pragma unroll
    for (int k = 0; k < K3; ++k) {
        const int dz = k / 9 - 1;
        const int dy = (k / 3) % 3 - 1;
        const int dx = k % 3 - 1;
        int zz = z + dz, yy = y + dy, xx = x + dx;
        bool ok = ((unsigned)zz < (unsigned)DIM_D) &
                  ((unsigned)yy < (unsigned)DIM_H) &
                  ((unsigned)xx < (unsigned)DIM_W);
        int zi = ok ? zz : 0;
        int yi = ok ? yy : 0;
        int xi = ok ? xx : 0;
        float r = pr[((size_t)zi * DIM_H + yi) * DIM_W + xi];
        r = ok ? r : 0.0f;
        r = (r < 0.0f) ? INFINITY : r;
        float d = fabsf(r - u);
        dist[k] = (k == CENTER) ? 0.0f : d;
    }
    float bd[KNN]; int bk[KNN];
#pragma unroll
    for (int j = 0; j < KNN; ++j) { bd[j] = INFINITY; bk[j] = -1; }
#pragma unroll
    for (int k = 0; k < K3; ++k) {
        float dcur = dist[k]; int kcur = k;
#pragma unroll
        for (int j = 0; j < KNN; ++j) {
            bool take = dcur < bd[j];
            float td = bd[j]; int tk = bk[j];
            bd[j] = take ? dcur : bd[j];
            bk[j] = take ? kcur : bk[j];
            dcur = take ? td : dcur;
            kcur = take ? tk : kcur;
        }
    }
    int votes[KNN];
#pragma unroll
    for (int j = 0; j < KNN; ++j) {
        int k = bk[j];
        const int dz = k / 9 - 1;
        const int dy = (k / 3) % 3 - 1;
        const int dx = k % 3 - 1;
        int zz = z + dz, yy = y + dy, xx = x + dx;
        bool ok = ((unsigned)zz < (unsigned)DIM_D) &
                  ((unsigned)yy < (unsigned)DIM_H) &
                  ((unsigned)xx < (unsigned)DIM_W);
        int zi = ok ? zz : 0;
        int yi = ok ? yy : 0;
        int xi = ok ? xx : 0;
        int cls = pa[((size_t)zi * DIM_H + yi) * DIM_W + xi];
        cls = ok ? cls : 0;
        cls = (bd[j] > 1.0f) ? NCLASSES : cls;
        votes[j] = cls;
    }
    int best_cnt = 0, best_cls = 1;
#pragma unroll
    for (int j = 0; j < KNN; ++j) {
        int v = votes[j];
        if (v >= 1 && v <= NCLASSES - 1) {
            int cnt = 0;
#pragma unroll
            for (int i = 0; i < KNN; ++i) cnt += (votes[i] == v) ? 1 : 0;
            if (cnt > best_cnt || (cnt == best_cnt && v < best_cls)) {
                best_cnt = cnt; best_cls = v;
            }
        }
    }
    out[p] = best_cls;
}

extern "C" void kernel_launch(void* const* d_in, const int* in_sizes, int n_in,
                              void* d_out, int out_size, void* d_ws, size_t ws_size,
                              hipStream_t stream) {
    const float* pr = (const float*)d_in[0];
    const float* ur = (const float*)d_in[1];
    const int*   pa = (const int*)d_in[2];
    const int*   px = (const int*)d_in[3];
    const int*   py = (const int*)d_in[4];
    const int*   pz = (const int*)d_in[5];
    int* out = (int*)d_out;
    int P = in_sizes[1];
    int gridH = (P + 4095) / 4096;
    int gridB = (P + BIN_PTS - 1) / BIN_PTS;
    int gridM = (P + 511) / 512;

    size_t h_b   = (size_t)RADIX * 4;                 // 1 KB
    size_t t_b   = (size_t)RADIX * 4;                 // 1 KB
    size_t m_b   = (size_t)RADIX * (size_t)gridB * 4; // ~512 KB
    size_t m_off = (h_b + t_b + m_b + 15) & ~(size_t)15;
    size_t pay_b = (size_t)P * 16;
    size_t need_stable = m_off + 2 * pay_b;

    if (ws_size >= need_stable) {
        char* ws = (char*)d_ws;
        unsigned* h0   = (unsigned*)ws;
        unsigned* T    = (unsigned*)(ws + h_b);
        unsigned* M    = (unsigned*)(ws + h_b + t_b);
        uint4*    pay1 = (uint4*)(ws + m_off);
        uint4*    pay2 = (uint4*)(ws + m_off + pay_b);

        // zero h0 + T + M in one memset
        hipMemsetAsync(ws, 0, h_b + t_b + m_b, stream);
        hist0_kernel<<<gridH, 256, 0, stream>>>(px, py, h0, P);
        scan256_kernel<<<1, 256, 0, stream>>>(h0);
        bin_pass1_kernel<<<gridB, BIN_THREADS, 0, stream>>>(
            ur, px, py, pz, h0, pay1, M, gridB, P);
        scan_digit_kernel<<<RADIX, 1024, 0, stream>>>(M, T, gridB);
        scan256_kernel<<<1, 256, 0, stream>>>(T);
        bin_pass2_stable_kernel<<<gridB, BIN_THREADS, 0, stream>>>(
            pay1, M, T, pay2, gridB, P);
        bev_knn_aos2_kernel<<<gridM, 256, 0, stream>>>(pr, pa, pay2, out, P);
    } else {
        int grid = (P + 255) / 256;
        bev_knn_direct_kernel<<<grid, 256, 0, stream>>>(pr, pa, ur, px, py,
                                                        pz, out, P);
    }
}

// Round 10
// 239.678 us; speedup vs baseline: 1.0271x; 1.0271x over previous
//
#include <hip/hip_runtime.h>
#include <hip/hip_bf16.h>
#include <math.h>

#define KNN 5
#define K3 27
#define CENTER 13
#define NCLASSES 21
#define DIM_D 32
#define DIM_H 128
#define DIM_W 2048

#define RADIX 256
#define BIN_PTS 2048
#define BIN_THREADS 256
#define NG 8192          // groups g' = y<<6 | (x>>10)<<5 | z
#define ROWW 1032        // staged row: [3]=left halo, [4..1027]=core, [1028]=right halo
#define SEG_TILE 2048

// Sort plan (grouping-exact, no stability needed):
//   pass 1: bin by seg = y<<1 | x>>10  (256 bins, global chunk-reserve cursors)
//   pass 2: one block per segment; z-histogram -> exact global bases
//           (LDS-local cursors, NO global atomics, deterministic), emits st[].
//   final order grouped exactly by g' = (seg<<5)|z; intra-group order arbitrary
//   (irrelevant: per-point independent compute, scatter to out[orig_idx]).

__device__ __forceinline__ unsigned seg_of_xy(int x, int y) {
    return ((unsigned)y << 1) | ((unsigned)x >> 10);
}
__device__ __forceinline__ unsigned seg_of_wy(unsigned wy) {
    return (((wy >> 11) & 0x7Fu) << 1) | ((wy >> 10) & 1u);
}

// ---------------- seg histogram ----------------
__global__ __launch_bounds__(256) void hist0_kernel(
    const int* __restrict__ px, const int* __restrict__ py,
    unsigned* __restrict__ h0, int P)
{
    __shared__ unsigned lh0[RADIX];
    int t = threadIdx.x;
    lh0[t] = 0;
    __syncthreads();
    int base4 = blockIdx.x * 1024 + t;
#pragma unroll
    for (int g = 0; g < 4; ++g) {
        int i4 = base4 + g * 256;
        int i0 = i4 * 4;
        if (i0 + 3 < P) {
            int4 X = ((const int4*)px)[i4];
            int4 Y = ((const int4*)py)[i4];
            atomicAdd(&lh0[seg_of_xy(X.x, Y.x)], 1u);
            atomicAdd(&lh0[seg_of_xy(X.y, Y.y)], 1u);
            atomicAdd(&lh0[seg_of_xy(X.z, Y.z)], 1u);
            atomicAdd(&lh0[seg_of_xy(X.w, Y.w)], 1u);
        } else {
            for (int i = i0; i < P; ++i)
                atomicAdd(&lh0[seg_of_xy(px[i], py[i])], 1u);
        }
    }
    __syncthreads();
    if (lh0[t]) atomicAdd(&h0[t], lh0[t]);
}

// exclusive scan of 256 entries; result to BOTH h (pass-1 cursors) and hbase
// (pristine segment starts for pass 2)
__global__ __launch_bounds__(256) void scan256_dup_kernel(
    unsigned* __restrict__ h, unsigned* __restrict__ hbase)
{
    __shared__ unsigned ws[4];
    int t = threadIdx.x, lane = t & 63, wid = t >> 6;
    unsigned a = h[t], ia = a;
#pragma unroll
    for (int off = 1; off < 64; off <<= 1) {
        unsigned v = __shfl_up(ia, off);
        if (lane >= off) ia += v;
    }
    if (lane == 63) ws[wid] = ia;
    __syncthreads();
    unsigned b = 0;
#pragma unroll
    for (int w = 0; w < 4; ++w) b += (w < wid) ? ws[w] : 0u;
    unsigned excl = b + ia - a;
    h[t] = excl;
    hbase[t] = excl;
}

// ---------------- pass 1: bin by seg ----------------
struct BinShared {
    unsigned lh[RADIX];
    unsigned lscan[RADIX];
    unsigned gbase[RADIX];
    unsigned wsum[4];
    uint4 stage[BIN_PTS];   // 32 KB
};

__device__ __forceinline__ void bin_local_scan(BinShared& S, int t)
{
    int lane = t & 63, wid = t >> 6;
    unsigned c = S.lh[t];
    unsigned inc = c;
#pragma unroll
    for (int off = 1; off < 64; off <<= 1) {
        unsigned v = __shfl_up(inc, off);
        if (lane >= off) inc += v;
    }
    if (lane == 63) S.wsum[wid] = inc;
    __syncthreads();
    unsigned wb = 0;
#pragma unroll
    for (int w = 0; w < 4; ++w) wb += (w < wid) ? S.wsum[w] : 0u;
    S.lscan[t] = wb + inc - c;
}

__global__ __launch_bounds__(BIN_THREADS) void bin_pass1_kernel(
    const float* __restrict__ ur, const int* __restrict__ px,
    const int* __restrict__ py, const int* __restrict__ pz,
    unsigned* __restrict__ g0, uint4* __restrict__ outp, int P)
{
    __shared__ BinShared S;
    int t = threadIdx.x;
    int bstart = blockIdx.x * BIN_PTS;
    int n = min(BIN_PTS, P - bstart);
    S.lh[t] = 0;
    __syncthreads();

    uint4 pay[8];
    unsigned rk[8], dg[8];
#pragma unroll
    for (int g = 0; g < 2; ++g) {
        int i4 = (bstart >> 2) + g * 256 + t;
        int i0 = i4 * 4;
        if (i0 + 3 < P) {
            int4 X = ((const int4*)px)[i4];
            int4 Y = ((const int4*)py)[i4];
            int4 Z = ((const int4*)pz)[i4];
            float4 U = ((const float4*)ur)[i4];
            int xs[4] = {X.x, X.y, X.z, X.w};
            int ys[4] = {Y.x, Y.y, Y.z, Y.w};
            int zs[4] = {Z.x, Z.y, Z.z, Z.w};
            float us[4] = {U.x, U.y, U.z, U.w};
#pragma unroll
            for (int c = 0; c < 4; ++c) {
                int j = g * 4 + c;
                dg[j] = seg_of_xy(xs[c], ys[c]);
                rk[j] = atomicAdd(&S.lh[dg[j]], 1u);
                pay[j] = make_uint4(__float_as_uint(us[c]),
                    (unsigned)xs[c] | ((unsigned)ys[c] << 11) | ((unsigned)zs[c] << 18),
                    (unsigned)(i0 + c), 0u);
            }
        } else {
#pragma unroll
            for (int c = 0; c < 4; ++c) {
                int j = g * 4 + c;
                int gi = i0 + c;
                if (gi < P) {
                    int x = px[gi], y = py[gi], z = pz[gi];
                    dg[j] = seg_of_xy(x, y);
                    rk[j] = atomicAdd(&S.lh[dg[j]], 1u);
                    pay[j] = make_uint4(__float_as_uint(ur[gi]),
                        (unsigned)x | ((unsigned)y << 11) | ((unsigned)z << 18),
                        (unsigned)gi, 0u);
                } else {
                    dg[j] = 0xFFFFFFFFu;
                }
            }
        }
    }
    __syncthreads();
    bin_local_scan(S, t);
    S.gbase[t] = S.lh[t] ? atomicAdd(&g0[t], S.lh[t]) : 0u;
    __syncthreads();
#pragma unroll
    for (int j = 0; j < 8; ++j)
        if (dg[j] != 0xFFFFFFFFu)
            S.stage[S.lscan[dg[j]] + rk[j]] = pay[j];
    __syncthreads();
#pragma unroll
    for (int j = 0; j < 8; ++j) {
        int s = j * 256 + t;
        if (s < n) {
            uint4 v = S.stage[s];
            unsigned d = seg_of_wy(v.y);
            unsigned pos = S.gbase[d] + ((unsigned)s - S.lscan[d]);
            outp[pos] = v;
        }
    }
}

// ---------------- pass 2: per-segment z-scatter (deterministic) ----------------
__global__ __launch_bounds__(256) void pass2z_kernel(
    const uint4* __restrict__ inp, const unsigned* __restrict__ segBase,
    uint4* __restrict__ outp, unsigned* __restrict__ st, int P)
{
    __shared__ unsigned zh[32];    // full-segment z histogram
    __shared__ unsigned cur[32];   // running global cursor per z
    __shared__ unsigned lz[32];    // per-tile z counts (rank source)
    __shared__ unsigned lsc[32];   // per-tile exclusive scan
    __shared__ uint4 stage[SEG_TILE];

    int b = blockIdx.x;
    unsigned s0 = segBase[b];
    unsigned s1 = (b == RADIX - 1) ? (unsigned)P : segBase[b + 1];
    int t = threadIdx.x;

    if (t < 32) zh[t] = 0;
    __syncthreads();

    // sweep 1: z histogram of the whole segment
    for (unsigned i = s0 + t; i < s1; i += 256)
        atomicAdd(&zh[(inp[i].y >> 18) & 31u], 1u);
    __syncthreads();

    // exclusive scan over 32 bins (wave 0, all 64 lanes active for shfl)
    if (t < 64) {
        unsigned v = (t < 32) ? zh[t] : 0u;
        unsigned iv = v;
#pragma unroll
        for (int off = 1; off < 32; off <<= 1) {
            unsigned u = __shfl_up(iv, off);
            if (t >= off) iv += u;
        }
        if (t < 32) {
            unsigned base = s0 + iv - v;
            cur[t] = base;
            st[b * 32 + t] = base;   // exact group start for the KNN kernel
        }
    }
    __syncthreads();

    // sweep 2: tiles -> LDS z-order stage -> coalesced chunked write-out
    for (unsigned tb = s0; tb < s1; tb += SEG_TILE) {
        unsigned m = min((unsigned)SEG_TILE, s1 - tb);
        if (t < 32) lz[t] = 0;
        __syncthreads();
        uint4 pay[8];
        unsigned rk[8], zz[8];
#pragma unroll
        for (int j = 0; j < 8; ++j) {
            int s = j * 256 + t;
            if (s < (int)m) {
                uint4 v = inp[tb + (unsigned)s];
                pay[j] = v;
                zz[j] = (v.y >> 18) & 31u;
                rk[j] = atomicAdd(&lz[zz[j]], 1u);
            } else {
                zz[j] = 0xFFFFFFFFu;
            }
        }
        __syncthreads();
        if (t < 64) {
            unsigned v = (t < 32) ? lz[t] : 0u;
            unsigned iv = v;
#pragma unroll
            for (int off = 1; off < 32; off <<= 1) {
                unsigned u = __shfl_up(iv, off);
                if (t >= off) iv += u;
            }
            if (t < 32) lsc[t] = iv - v;
        }
        __syncthreads();
#pragma unroll
        for (int j = 0; j < 8; ++j)
            if (zz[j] != 0xFFFFFFFFu)
                stage[lsc[zz[j]] + rk[j]] = pay[j];
        __syncthreads();
#pragma unroll
        for (int j = 0; j < 8; ++j) {
            int s = j * 256 + t;
            if (s < (int)m) {
                uint4 v = stage[s];
                unsigned z = (v.y >> 18) & 31u;
                outp[cur[z] + ((unsigned)s - lsc[z])] = v;
            }
        }
        __syncthreads();
        if (t < 32) cur[t] += lz[t];
        __syncthreads();
    }
}

// ---------------- KNN main kernel: LDS-staged neighborhoods ----------------
__device__ __forceinline__ int swizzle_block(int b, int nb) {
    if ((nb & 7) == 0) {
        int per = nb >> 3;
        return (b & 7) * per + (b >> 3);
    }
    return b;
}

__global__ __launch_bounds__(256) void bev_knn_lds_kernel(
    const float* __restrict__ pr, const int* __restrict__ pa,
    const uint4* __restrict__ payload, const unsigned* __restrict__ st,
    int* __restrict__ out, int P)
{
    __shared__ float prs[9 * ROWW];
    __shared__ unsigned char pas[9 * ROWW];

    int lb = swizzle_block(blockIdx.x, gridDim.x);   // g' = y<<6 | xb<<5 | z
    unsigned start = st[lb];
    unsigned end   = (lb == NG - 1) ? (unsigned)P : st[lb + 1];
    int cnt = (int)end - (int)start;
    if (cnt <= 0) return;

    int y  = lb >> 6;
    int x0 = ((lb >> 5) & 1) << 10;
    int z  = lb & 31;
    int t  = threadIdx.x;

    // stage 9 (z±1, y±1) rows of pr (f32) + pa (u8), zero-filled outside the
    // volume (exactly reproduces the reference's zero padding)
    for (int r = 0; r < 9; ++r) {
        int gz = z + r / 3 - 1;
        int gy = y + r % 3 - 1;
        bool inb = ((unsigned)gz < (unsigned)DIM_D) &
                   ((unsigned)gy < (unsigned)DIM_H);
        size_t rb = ((size_t)(gz * DIM_H + gy) << 11) + x0;
        float4 f = make_float4(0.f, 0.f, 0.f, 0.f);
        unsigned pk = 0u;
        if (inb) {
            f = ((const float4*)(pr + rb))[t];
            int4 a = ((const int4*)(pa + rb))[t];
            pk = (unsigned)a.x | ((unsigned)a.y << 8) |
                 ((unsigned)a.z << 16) | ((unsigned)a.w << 24);
        }
        ((float4*)(prs + r * ROWW + 4))[t] = f;
        ((unsigned*)(pas + r * ROWW + 4))[t] = pk;
        if (t == 0) {
            bool okl = inb && (x0 > 0);
            prs[r * ROWW + 3] = okl ? pr[rb - 1] : 0.f;
            pas[r * ROWW + 3] = okl ? (unsigned char)pa[rb - 1] : (unsigned char)0;
            bool okr = inb && (x0 + 1024 < DIM_W);
            prs[r * ROWW + 1028] = okr ? pr[rb + 1024] : 0.f;
            pas[r * ROWW + 1028] = okr ? (unsigned char)pa[rb + 1024] : (unsigned char)0;
        }
    }
    __syncthreads();

    for (int i = t; i < cnt; i += 256) {
        uint4 w = payload[start + i];
        float u = __uint_as_float(w.x);
        int xi = (int)(w.y & 1023u) + 4;   // x - x0 + 4

        float dist[K3];
#pragma unroll
        for (int k = 0; k < K3; ++k) {
            float r = prs[(k / 3) * ROWW + xi + (k % 3) - 1];
            r = (r < 0.0f) ? INFINITY : r;
            float d = fabsf(r - u);
            dist[k] = (k == CENTER) ? 0.0f : d;
        }

        // top-5 smallest, ties -> lower flat index (lax.top_k semantics)
        float bd[KNN];
        int   bk[KNN];
#pragma unroll
        for (int j = 0; j < KNN; ++j) { bd[j] = INFINITY; bk[j] = -1; }
#pragma unroll
        for (int k = 0; k < K3; ++k) {
            float dcur = dist[k];
            int   kcur = k;
#pragma unroll
            for (int j = 0; j < KNN; ++j) {
                bool take = dcur < bd[j];
                float td = bd[j]; int tk = bk[j];
                bd[j] = take ? dcur : bd[j];
                bk[j] = take ? kcur : bk[j];
                dcur  = take ? td : dcur;
                kcur  = take ? tk : kcur;
            }
        }

        int votes[KNN];
#pragma unroll
        for (int j = 0; j < KNN; ++j) {
            int k = bk[j];
            int cls = (int)pas[(k / 3) * ROWW + xi + (k % 3) - 1];
            cls = (bd[j] > 1.0f) ? NCLASSES : cls;
            votes[j] = cls;
        }

        int best_cnt = 0, best_cls = 1;
#pragma unroll
        for (int j = 0; j < KNN; ++j) {
            int v = votes[j];
            if (v >= 1 && v <= NCLASSES - 1) {
                int c2 = 0;
#pragma unroll
                for (int q = 0; q < KNN; ++q) c2 += (votes[q] == v) ? 1 : 0;
                if (c2 > best_cnt || (c2 == best_cnt && v < best_cls)) {
                    best_cnt = c2;
                    best_cls = v;
                }
            }
        }
        out[w.z] = best_cls;
    }
}

// ---------------- direct fallback (R1-proven) ----------------
__global__ __launch_bounds__(256) void bev_knn_direct_kernel(
    const float* __restrict__ pr, const int* __restrict__ pa,
    const float* __restrict__ ur, const int* __restrict__ px,
    const int* __restrict__ py, const int* __restrict__ pz,
    int* __restrict__ out, int P)
{
    int p = blockIdx.x * blockDim.x + threadIdx.x;
    if (p >= P) return;
    float u = ur[p];
    int x = px[p], y = py[p], z = pz[p];
    float dist[K3];
#pragma unroll
    for (int k = 0; k < K3; ++k) {
        const int dz = k / 9 - 1;
        const int dy = (k / 3) % 3 - 1;
        const int dx = k % 3 - 1;
        int zz = z + dz, yy = y + dy, xx = x + dx;
        bool ok = ((unsigned)zz < (unsigned)DIM_D) &
                  ((unsigned)yy < (unsigned)DIM_H) &
                  ((unsigned)xx < (unsigned)DIM_W);
        int zi = ok ? zz : 0;
        int yi = ok ? yy : 0;
        int xi = ok ? xx : 0;
        float r = pr[((size_t)zi * DIM_H + yi) * DIM_W + xi];
        r = ok ? r : 0.0f;
        r = (r < 0.0f) ? INFINITY : r;
        float d = fabsf(r - u);
        dist[k] = (k == CENTER) ? 0.0f : d;
    }
    float bd[KNN]; int bk[KNN];
#pragma unroll
    for (int j = 0; j < KNN; ++j) { bd[j] = INFINITY; bk[j] = -1; }
#pragma unroll
    for (int k = 0; k < K3; ++k) {
        float dcur = dist[k]; int kcur = k;
#pragma unroll
        for (int j = 0; j < KNN; ++j) {
            bool take = dcur < bd[j];
            float td = bd[j]; int tk = bk[j];
            bd[j] = take ? dcur : bd[j];
            bk[j] = take ? kcur : bk[j];
            dcur = take ? td : dcur;
            kcur = take ? tk : kcur;
        }
    }
    int votes[KNN];
#pragma unroll
    for (int j = 0; j < KNN; ++j) {
        int k = bk[j];
        const int dz = k / 9 - 1;
        const int dy = (k / 3) % 3 - 1;
        const int dx = k % 3 - 1;
        int zz = z + dz, yy = y + dy, xx = x + dx;
        bool ok = ((unsigned)zz < (unsigned)DIM_D) &
                  ((unsigned)yy < (unsigned)DIM_H) &
                  ((unsigned)xx < (unsigned)DIM_W);
        int zi = ok ? zz : 0;
        int yi = ok ? yy : 0;
        int xi = ok ? xx : 0;
        int cls = pa[((size_t)zi * DIM_H + yi) * DIM_W + xi];
        cls = ok ? cls : 0;
        cls = (bd[j] > 1.0f) ? NCLASSES : cls;
        votes[j] = cls;
    }
    int best_cnt = 0, best_cls = 1;
#pragma unroll
    for (int j = 0; j < KNN; ++j) {
        int v = votes[j];
        if (v >= 1 && v <= NCLASSES - 1) {
            int cnt = 0;
#pragma unroll
            for (int i = 0; i < KNN; ++i) cnt += (votes[i] == v) ? 1 : 0;
            if (cnt > best_cnt || (cnt == best_cnt && v < best_cls)) {
                best_cnt = cnt; best_cls = v;
            }
        }
    }
    out[p] = best_cls;
}

extern "C" void kernel_launch(void* const* d_in, const int* in_sizes, int n_in,
                              void* d_out, int out_size, void* d_ws, size_t ws_size,
                              hipStream_t stream) {
    const float* pr = (const float*)d_in[0];
    const float* ur = (const float*)d_in[1];
    const int*   pa = (const int*)d_in[2];
    const int*   px = (const int*)d_in[3];
    const int*   py = (const int*)d_in[4];
    const int*   pz = (const int*)d_in[5];
    int* out = (int*)d_out;
    int P = in_sizes[1];
    int gridH = (P + 4095) / 4096;
    int gridB = (P + BIN_PTS - 1) / BIN_PTS;
    int gridD = (P + 255) / 256;

    size_t h_b   = (size_t)RADIX * 4;     // 1 KB cursors
    size_t hb_b  = (size_t)RADIX * 4;     // 1 KB pristine bases
    size_t st_b  = (size_t)NG * 4;        // 32 KB group starts
    size_t p_off = (h_b + hb_b + st_b + 15) & ~(size_t)15;
    size_t pay_b = (size_t)P * 16;
    size_t need  = p_off + 2 * pay_b;

    if (ws_size >= need) {
        char* ws = (char*)d_ws;
        unsigned* h0cur  = (unsigned*)ws;
        unsigned* h0base = (unsigned*)(ws + h_b);
        unsigned* st     = (unsigned*)(ws + h_b + hb_b);
        uint4*    pay1   = (uint4*)(ws + p_off);
        uint4*    pay2   = (uint4*)(ws + p_off + pay_b);

        hipMemsetAsync(h0cur, 0, h_b, stream);
        hist0_kernel<<<gridH, 256, 0, stream>>>(px, py, h0cur, P);
        scan256_dup_kernel<<<1, 256, 0, stream>>>(h0cur, h0base);
        bin_pass1_kernel<<<gridB, BIN_THREADS, 0, stream>>>(ur, px, py, pz,
                                                            h0cur, pay1, P);
        pass2z_kernel<<<RADIX, 256, 0, stream>>>(pay1, h0base, pay2, st, P);
        bev_knn_lds_kernel<<<NG, 256, 0, stream>>>(pr, pa, pay2, st, out, P);
    } else {
        bev_knn_direct_kernel<<<gridD, 256, 0, stream>>>(pr, pa, ur, px, py,
                                                         pz, out, P);
    }
}

// Round 11
// 207.263 us; speedup vs baseline: 1.1878x; 1.1564x over previous
//
#include <hip/hip_runtime.h>
#include <hip/hip_bf16.h>
#include <math.h>

#define KNN 5
#define K3 27
#define CENTER 13
#define NCLASSES 21
#define DIM_D 32
#define DIM_H 128
#define DIM_W 2048

#define RADIX 256
#define BIN_PTS 2048
#define BIN_THREADS 256
#define SEG_TILE 2048

// Sort plan (grouping-exact, deterministic, no stability requirement):
//   pass 1: bin by seg = y<<1 | x>>10        (256 bins, global cursor reserve)
//   pass 2: one block per segment; bin by b8 = (z<<3)|(x>>7 & 7)
//           exact bases from full-segment histogram; LDS cursors; NO global
//           atomics. Final order: (y, x10, z, x9..7) -> a wave holds points
//           with fixed (y,z) in a ~512-wide x window = R6's proven locality.

__device__ __forceinline__ unsigned seg_of_xy(int x, int y) {
    return ((unsigned)y << 1) | ((unsigned)x >> 10);
}
__device__ __forceinline__ unsigned seg_of_wy(unsigned wy) {
    return (((wy >> 11) & 0x7Fu) << 1) | ((wy >> 10) & 1u);
}
__device__ __forceinline__ unsigned b8_of_wy(unsigned wy) {
    return (((wy >> 18) & 31u) << 3) | ((wy >> 7) & 7u);
}

// ---------------- seg histogram ----------------
__global__ __launch_bounds__(256) void hist0_kernel(
    const int* __restrict__ px, const int* __restrict__ py,
    unsigned* __restrict__ h0, int P)
{
    __shared__ unsigned lh0[RADIX];
    int t = threadIdx.x;
    lh0[t] = 0;
    __syncthreads();
    int base4 = blockIdx.x * 1024 + t;
#pragma unroll
    for (int g = 0; g < 4; ++g) {
        int i4 = base4 + g * 256;
        int i0 = i4 * 4;
        if (i0 + 3 < P) {
            int4 X = ((const int4*)px)[i4];
            int4 Y = ((const int4*)py)[i4];
            atomicAdd(&lh0[seg_of_xy(X.x, Y.x)], 1u);
            atomicAdd(&lh0[seg_of_xy(X.y, Y.y)], 1u);
            atomicAdd(&lh0[seg_of_xy(X.z, Y.z)], 1u);
            atomicAdd(&lh0[seg_of_xy(X.w, Y.w)], 1u);
        } else {
            for (int i = i0; i < P; ++i)
                atomicAdd(&lh0[seg_of_xy(px[i], py[i])], 1u);
        }
    }
    __syncthreads();
    if (lh0[t]) atomicAdd(&h0[t], lh0[t]);
}

// exclusive scan of 256 entries; result to BOTH h (pass-1 cursors) and hbase
__global__ __launch_bounds__(256) void scan256_dup_kernel(
    unsigned* __restrict__ h, unsigned* __restrict__ hbase)
{
    __shared__ unsigned ws[4];
    int t = threadIdx.x, lane = t & 63, wid = t >> 6;
    unsigned a = h[t], ia = a;
#pragma unroll
    for (int off = 1; off < 64; off <<= 1) {
        unsigned v = __shfl_up(ia, off);
        if (lane >= off) ia += v;
    }
    if (lane == 63) ws[wid] = ia;
    __syncthreads();
    unsigned b = 0;
#pragma unroll
    for (int w = 0; w < 4; ++w) b += (w < wid) ? ws[w] : 0u;
    unsigned excl = b + ia - a;
    h[t] = excl;
    hbase[t] = excl;
}

// ---------------- pass 1: bin by seg ----------------
struct BinShared {
    unsigned lh[RADIX];
    unsigned lscan[RADIX];
    unsigned gbase[RADIX];
    unsigned wsum[4];
    uint4 stage[BIN_PTS];   // 32 KB
};

__device__ __forceinline__ void bin_local_scan(BinShared& S, int t)
{
    int lane = t & 63, wid = t >> 6;
    unsigned c = S.lh[t];
    unsigned inc = c;
#pragma unroll
    for (int off = 1; off < 64; off <<= 1) {
        unsigned v = __shfl_up(inc, off);
        if (lane >= off) inc += v;
    }
    if (lane == 63) S.wsum[wid] = inc;
    __syncthreads();
    unsigned wb = 0;
#pragma unroll
    for (int w = 0; w < 4; ++w) wb += (w < wid) ? S.wsum[w] : 0u;
    S.lscan[t] = wb + inc - c;
}

__global__ __launch_bounds__(BIN_THREADS) void bin_pass1_kernel(
    const float* __restrict__ ur, const int* __restrict__ px,
    const int* __restrict__ py, const int* __restrict__ pz,
    unsigned* __restrict__ g0, uint4* __restrict__ outp, int P)
{
    __shared__ BinShared S;
    int t = threadIdx.x;
    int bstart = blockIdx.x * BIN_PTS;
    int n = min(BIN_PTS, P - bstart);
    S.lh[t] = 0;
    __syncthreads();

    uint4 pay[8];
    unsigned rk[8], dg[8];
#pragma unroll
    for (int g = 0; g < 2; ++g) {
        int i4 = (bstart >> 2) + g * 256 + t;
        int i0 = i4 * 4;
        if (i0 + 3 < P) {
            int4 X = ((const int4*)px)[i4];
            int4 Y = ((const int4*)py)[i4];
            int4 Z = ((const int4*)pz)[i4];
            float4 U = ((const float4*)ur)[i4];
            int xs[4] = {X.x, X.y, X.z, X.w};
            int ys[4] = {Y.x, Y.y, Y.z, Y.w};
            int zs[4] = {Z.x, Z.y, Z.z, Z.w};
            float us[4] = {U.x, U.y, U.z, U.w};
#pragma unroll
            for (int c = 0; c < 4; ++c) {
                int j = g * 4 + c;
                dg[j] = seg_of_xy(xs[c], ys[c]);
                rk[j] = atomicAdd(&S.lh[dg[j]], 1u);
                pay[j] = make_uint4(__float_as_uint(us[c]),
                    (unsigned)xs[c] | ((unsigned)ys[c] << 11) | ((unsigned)zs[c] << 18),
                    (unsigned)(i0 + c), 0u);
            }
        } else {
#pragma unroll
            for (int c = 0; c < 4; ++c) {
                int j = g * 4 + c;
                int gi = i0 + c;
                if (gi < P) {
                    int x = px[gi], y = py[gi], z = pz[gi];
                    dg[j] = seg_of_xy(x, y);
                    rk[j] = atomicAdd(&S.lh[dg[j]], 1u);
                    pay[j] = make_uint4(__float_as_uint(ur[gi]),
                        (unsigned)x | ((unsigned)y << 11) | ((unsigned)z << 18),
                        (unsigned)gi, 0u);
                } else {
                    dg[j] = 0xFFFFFFFFu;
                }
            }
        }
    }
    __syncthreads();
    bin_local_scan(S, t);
    S.gbase[t] = S.lh[t] ? atomicAdd(&g0[t], S.lh[t]) : 0u;
    __syncthreads();
#pragma unroll
    for (int j = 0; j < 8; ++j)
        if (dg[j] != 0xFFFFFFFFu)
            S.stage[S.lscan[dg[j]] + rk[j]] = pay[j];
    __syncthreads();
#pragma unroll
    for (int j = 0; j < 8; ++j) {
        int s = j * 256 + t;
        if (s < n) {
            uint4 v = S.stage[s];
            unsigned d = seg_of_wy(v.y);
            unsigned pos = S.gbase[d] + ((unsigned)s - S.lscan[d]);
            outp[pos] = v;
        }
    }
}

// ---------------- pass 2: per-segment (z,x97) scatter, deterministic ----------------
__global__ __launch_bounds__(256) void pass2b_kernel(
    const uint4* __restrict__ inp, const unsigned* __restrict__ segBase,
    uint4* __restrict__ outp, int P)
{
    __shared__ unsigned bh[RADIX];    // full-segment bin histogram
    __shared__ unsigned cur[RADIX];   // running global cursor per bin
    __shared__ unsigned lz[RADIX];    // per-tile counts
    __shared__ unsigned lsc[RADIX];   // per-tile exclusive scan
    __shared__ unsigned wsum[4];
    __shared__ uint4 stage[SEG_TILE]; // 32 KB

    int b = blockIdx.x;
    unsigned s0 = segBase[b];
    unsigned s1 = (b == RADIX - 1) ? (unsigned)P : segBase[b + 1];
    int t = threadIdx.x, lane = t & 63, wid = t >> 6;

    bh[t] = 0;
    __syncthreads();

    // sweep 1: full-segment bin histogram
    for (unsigned i = s0 + t; i < s1; i += 256)
        atomicAdd(&bh[b8_of_wy(inp[i].y)], 1u);
    __syncthreads();

    // block-wide exclusive scan of 256 bins -> global bases
    {
        unsigned c = bh[t], inc = c;
#pragma unroll
        for (int off = 1; off < 64; off <<= 1) {
            unsigned v = __shfl_up(inc, off);
            if (lane >= off) inc += v;
        }
        if (lane == 63) wsum[wid] = inc;
        __syncthreads();
        unsigned wb = 0;
#pragma unroll
        for (int w = 0; w < 4; ++w) wb += (w < wid) ? wsum[w] : 0u;
        cur[t] = s0 + wb + inc - c;
    }
    __syncthreads();

    // sweep 2: tiles -> LDS reorder -> coalesced chunked write-out
    for (unsigned tb = s0; tb < s1; tb += SEG_TILE) {
        unsigned m = min((unsigned)SEG_TILE, s1 - tb);
        lz[t] = 0;
        __syncthreads();
        uint4 pay[8];
        unsigned rk[8], zz[8];
#pragma unroll
        for (int j = 0; j < 8; ++j) {
            int s = j * 256 + t;
            if (s < (int)m) {
                uint4 v = inp[tb + (unsigned)s];
                pay[j] = v;
                zz[j] = b8_of_wy(v.y);
                rk[j] = atomicAdd(&lz[zz[j]], 1u);
            } else {
                zz[j] = 0xFFFFFFFFu;
            }
        }
        __syncthreads();
        {
            unsigned c = lz[t], inc = c;
#pragma unroll
            for (int off = 1; off < 64; off <<= 1) {
                unsigned v = __shfl_up(inc, off);
                if (lane >= off) inc += v;
            }
            if (lane == 63) wsum[wid] = inc;
            __syncthreads();
            unsigned wb = 0;
#pragma unroll
            for (int w = 0; w < 4; ++w) wb += (w < wid) ? wsum[w] : 0u;
            lsc[t] = wb + inc - c;
        }
        __syncthreads();
#pragma unroll
        for (int j = 0; j < 8; ++j)
            if (zz[j] != 0xFFFFFFFFu)
                stage[lsc[zz[j]] + rk[j]] = pay[j];
        __syncthreads();
#pragma unroll
        for (int j = 0; j < 8; ++j) {
            int s = j * 256 + t;
            if (s < (int)m) {
                uint4 v = stage[s];
                unsigned d = b8_of_wy(v.y);
                outp[cur[d] + ((unsigned)s - lsc[d])] = v;
            }
        }
        __syncthreads();
        cur[t] += lz[t];
        __syncthreads();
    }
}

// ---------------- KNN main kernel (R6-proven gather body) ----------------
__device__ __forceinline__ int swizzle_block(int b, int nb) {
    if ((nb & 7) == 0) {
        int per = nb >> 3;
        return (b & 7) * per + (b >> 3);
    }
    return b;
}

__device__ __forceinline__ void bev_knn_body(
    const float* __restrict__ pr, const int* __restrict__ pa,
    float u, int x, int y, int z, int oidx, int* __restrict__ out)
{
    float dist[K3];
#pragma unroll
    for (int k = 0; k < K3; ++k) {
        const int dz = k / 9 - 1;
        const int dy = (k / 3) % 3 - 1;
        const int dx = k % 3 - 1;
        int zz = z + dz, yy = y + dy, xx = x + dx;
        bool ok = ((unsigned)zz < (unsigned)DIM_D) &
                  ((unsigned)yy < (unsigned)DIM_H) &
                  ((unsigned)xx < (unsigned)DIM_W);
        int zi = ok ? zz : 0;
        int yi = ok ? yy : 0;
        int xi = ok ? xx : 0;
        float r = pr[((size_t)zi * DIM_H + yi) * DIM_W + xi];
        r = ok ? r : 0.0f;
        r = (r < 0.0f) ? INFINITY : r;
        float d = fabsf(r - u);
        dist[k] = (k == CENTER) ? 0.0f : d;
    }

    float bd[KNN];
    int   bk[KNN];
#pragma unroll
    for (int j = 0; j < KNN; ++j) { bd[j] = INFINITY; bk[j] = -1; }
#pragma unroll
    for (int k = 0; k < K3; ++k) {
        float dcur = dist[k];
        int   kcur = k;
#pragma unroll
        for (int j = 0; j < KNN; ++j) {
            bool take = dcur < bd[j];
            float td = bd[j]; int tk = bk[j];
            bd[j] = take ? dcur : bd[j];
            bk[j] = take ? kcur : bk[j];
            dcur  = take ? td : dcur;
            kcur  = take ? tk : kcur;
        }
    }

    int votes[KNN];
#pragma unroll
    for (int j = 0; j < KNN; ++j) {
        int k = bk[j];
        const int dz = k / 9 - 1;
        const int dy = (k / 3) % 3 - 1;
        const int dx = k % 3 - 1;
        int zz = z + dz, yy = y + dy, xx = x + dx;
        bool ok = ((unsigned)zz < (unsigned)DIM_D) &
                  ((unsigned)yy < (unsigned)DIM_H) &
                  ((unsigned)xx < (unsigned)DIM_W);
        int zi = ok ? zz : 0;
        int yi = ok ? yy : 0;
        int xi = ok ? xx : 0;
        int cls = pa[((size_t)zi * DIM_H + yi) * DIM_W + xi];
        cls = ok ? cls : 0;
        cls = (bd[j] > 1.0f) ? NCLASSES : cls;
        votes[j] = cls;
    }

    int best_cnt = 0, best_cls = 1;
#pragma unroll
    for (int j = 0; j < KNN; ++j) {
        int v = votes[j];
        if (v >= 1 && v <= NCLASSES - 1) {
            int cnt = 0;
#pragma unroll
            for (int i = 0; i < KNN; ++i) cnt += (votes[i] == v) ? 1 : 0;
            if (cnt > best_cnt || (cnt == best_cnt && v < best_cls)) {
                best_cnt = cnt;
                best_cls = v;
            }
        }
    }
    out[oidx] = best_cls;
}

__global__ __launch_bounds__(256) void bev_knn_aos_kernel(
    const float* __restrict__ pr, const int* __restrict__ pa,
    const uint4* __restrict__ payload, int* __restrict__ out, int P)
{
    int lb = swizzle_block(blockIdx.x, gridDim.x);
    int p = lb * blockDim.x + threadIdx.x;
    if (p >= P) return;
    uint4 w = payload[p];
    float u = __uint_as_float(w.x);
    int x = (int)(w.y & 0x7FFu);
    int y = (int)((w.y >> 11) & 0x7Fu);
    int z = (int)((w.y >> 18) & 0x1Fu);
    bev_knn_body(pr, pa, u, x, y, z, (int)w.z, out);
}

// ---------------- direct fallback ----------------
__global__ __launch_bounds__(256) void bev_knn_direct_kernel(
    const float* __restrict__ pr, const int* __restrict__ pa,
    const float* __restrict__ ur, const int* __restrict__ px,
    const int* __restrict__ py, const int* __restrict__ pz,
    int* __restrict__ out, int P)
{
    int p = blockIdx.x * blockDim.x + threadIdx.x;
    if (p >= P) return;
    bev_knn_body(pr, pa, ur[p], px[p], py[p], pz[p], p, out);
}

extern "C" void kernel_launch(void* const* d_in, const int* in_sizes, int n_in,
                              void* d_out, int out_size, void* d_ws, size_t ws_size,
                              hipStream_t stream) {
    const float* pr = (const float*)d_in[0];
    const float* ur = (const float*)d_in[1];
    const int*   pa = (const int*)d_in[2];
    const int*   px = (const int*)d_in[3];
    const int*   py = (const int*)d_in[4];
    const int*   pz = (const int*)d_in[5];
    int* out = (int*)d_out;
    int P = in_sizes[1];
    int gridH = (P + 4095) / 4096;
    int gridB = (P + BIN_PTS - 1) / BIN_PTS;
    int gridD = (P + 255) / 256;

    size_t h_b   = (size_t)RADIX * 4;     // 1 KB cursors
    size_t hb_b  = (size_t)RADIX * 4;     // 1 KB pristine bases
    size_t p_off = (h_b + hb_b + 15) & ~(size_t)15;
    size_t pay_b = (size_t)P * 16;
    size_t need  = p_off + 2 * pay_b;

    if (ws_size >= need) {
        char* ws = (char*)d_ws;
        unsigned* h0cur  = (unsigned*)ws;
        unsigned* h0base = (unsigned*)(ws + h_b);
        uint4*    pay1   = (uint4*)(ws + p_off);
        uint4*    pay2   = (uint4*)(ws + p_off + pay_b);

        hipMemsetAsync(h0cur, 0, h_b, stream);
        hist0_kernel<<<gridH, 256, 0, stream>>>(px, py, h0cur, P);
        scan256_dup_kernel<<<1, 256, 0, stream>>>(h0cur, h0base);
        bin_pass1_kernel<<<gridB, BIN_THREADS, 0, stream>>>(ur, px, py, pz,
                                                            h0cur, pay1, P);
        pass2b_kernel<<<RADIX, 256, 0, stream>>>(pay1, h0base, pay2, P);
        bev_knn_aos_kernel<<<gridD, 256, 0, stream>>>(pr, pa, pay2, out, P);
    } else {
        bev_knn_direct_kernel<<<gridD, 256, 0, stream>>>(pr, pa, ur, px, py,
                                                         pz, out, P);
    }
}

// Round 12
// 199.287 us; speedup vs baseline: 1.2353x; 1.0400x over previous
//
#include <hip/hip_runtime.h>
#include <hip/hip_bf16.h>
#include <math.h>

#define KNN 5
#define K3 27
#define CENTER 13
#define NCLASSES 21
#define DIM_D 32
#define DIM_H 128
#define DIM_W 2048

#define RADIX 256
#define BIN_PTS 2048
#define SEG_TILE 2048

// Sort plan (grouping-exact, deterministic, no stability requirement):
//   pass 1 (512 thr): bin by seg = y<<1 | x>>10   (256 bins, global cursors)
//   pass 2 (1024 thr): one block per segment; bin by b8 = (z<<3)|(x>>7 & 7)
//           exact bases from full-segment histogram; LDS cursors; NO global
//           atomics. Final order: (y, x10, z, x9..7) — measured R10: main
//           kernel FETCH 45 MB (best locality so far), dur 72-78 us.

__device__ __forceinline__ unsigned seg_of_xy(int x, int y) {
    return ((unsigned)y << 1) | ((unsigned)x >> 10);
}
__device__ __forceinline__ unsigned seg_of_wy(unsigned wy) {
    return (((wy >> 11) & 0x7Fu) << 1) | ((wy >> 10) & 1u);
}
__device__ __forceinline__ unsigned b8_of_wy(unsigned wy) {
    return (((wy >> 18) & 31u) << 3) | ((wy >> 7) & 7u);
}

// ---------------- seg histogram ----------------
__global__ __launch_bounds__(256) void hist0_kernel(
    const int* __restrict__ px, const int* __restrict__ py,
    unsigned* __restrict__ h0, int P)
{
    __shared__ unsigned lh0[RADIX];
    int t = threadIdx.x;
    lh0[t] = 0;
    __syncthreads();
    int base4 = blockIdx.x * 1024 + t;
#pragma unroll
    for (int g = 0; g < 4; ++g) {
        int i4 = base4 + g * 256;
        int i0 = i4 * 4;
        if (i0 + 3 < P) {
            int4 X = ((const int4*)px)[i4];
            int4 Y = ((const int4*)py)[i4];
            atomicAdd(&lh0[seg_of_xy(X.x, Y.x)], 1u);
            atomicAdd(&lh0[seg_of_xy(X.y, Y.y)], 1u);
            atomicAdd(&lh0[seg_of_xy(X.z, Y.z)], 1u);
            atomicAdd(&lh0[seg_of_xy(X.w, Y.w)], 1u);
        } else {
            for (int i = i0; i < P; ++i)
                atomicAdd(&lh0[seg_of_xy(px[i], py[i])], 1u);
        }
    }
    __syncthreads();
    if (lh0[t]) atomicAdd(&h0[t], lh0[t]);
}

// exclusive scan of 256 entries; result to BOTH h (pass-1 cursors) and hbase
__global__ __launch_bounds__(256) void scan256_dup_kernel(
    unsigned* __restrict__ h, unsigned* __restrict__ hbase)
{
    __shared__ unsigned ws[4];
    int t = threadIdx.x, lane = t & 63, wid = t >> 6;
    unsigned a = h[t], ia = a;
#pragma unroll
    for (int off = 1; off < 64; off <<= 1) {
        unsigned v = __shfl_up(ia, off);
        if (lane >= off) ia += v;
    }
    if (lane == 63) ws[wid] = ia;
    __syncthreads();
    unsigned b = 0;
#pragma unroll
    for (int w = 0; w < 4; ++w) b += (w < wid) ? ws[w] : 0u;
    unsigned excl = b + ia - a;
    h[t] = excl;
    hbase[t] = excl;
}

// ---------------- pass 1: bin by seg, 512 threads (32 waves/CU at 4 blk/CU)
struct BinShared {
    unsigned lh[RADIX];
    unsigned lscan[RADIX];
    unsigned gbase[RADIX];
    unsigned wsum[4];
    uint4 stage[BIN_PTS];   // 32 KB
};

__global__ __launch_bounds__(512) void bin_pass1_kernel(
    const float* __restrict__ ur, const int* __restrict__ px,
    const int* __restrict__ py, const int* __restrict__ pz,
    unsigned* __restrict__ g0, uint4* __restrict__ outp, int P)
{
    __shared__ BinShared S;
    int t = threadIdx.x, lane = t & 63, wid = t >> 6;
    int bstart = blockIdx.x * BIN_PTS;
    int n = min(BIN_PTS, P - bstart);
    if (t < RADIX) S.lh[t] = 0;
    __syncthreads();

    // 4 points per thread via one int4/float4 load each
    uint4 pay[4];
    unsigned rk[4], dg[4];
    {
        int i4 = (bstart >> 2) + t;
        int i0 = i4 * 4;
        if (i0 + 3 < P) {
            int4 X = ((const int4*)px)[i4];
            int4 Y = ((const int4*)py)[i4];
            int4 Z = ((const int4*)pz)[i4];
            float4 U = ((const float4*)ur)[i4];
            int xs[4] = {X.x, X.y, X.z, X.w};
            int ys[4] = {Y.x, Y.y, Y.z, Y.w};
            int zs[4] = {Z.x, Z.y, Z.z, Z.w};
            float us[4] = {U.x, U.y, U.z, U.w};
#pragma unroll
            for (int c = 0; c < 4; ++c) {
                dg[c] = seg_of_xy(xs[c], ys[c]);
                rk[c] = atomicAdd(&S.lh[dg[c]], 1u);
                pay[c] = make_uint4(__float_as_uint(us[c]),
                    (unsigned)xs[c] | ((unsigned)ys[c] << 11) | ((unsigned)zs[c] << 18),
                    (unsigned)(i0 + c), 0u);
            }
        } else {
#pragma unroll
            for (int c = 0; c < 4; ++c) {
                int gi = i0 + c;
                if (gi < P) {
                    int x = px[gi], y = py[gi], z = pz[gi];
                    dg[c] = seg_of_xy(x, y);
                    rk[c] = atomicAdd(&S.lh[dg[c]], 1u);
                    pay[c] = make_uint4(__float_as_uint(ur[gi]),
                        (unsigned)x | ((unsigned)y << 11) | ((unsigned)z << 18),
                        (unsigned)gi, 0u);
                } else {
                    dg[c] = 0xFFFFFFFFu;
                }
            }
        }
    }
    __syncthreads();

    // exclusive scan over 256 bins (first 4 waves own the bins; barriers uniform)
    {
        unsigned c0 = (t < RADIX) ? S.lh[t] : 0u;
        unsigned inc = c0;
#pragma unroll
        for (int off = 1; off < 64; off <<= 1) {
            unsigned v = __shfl_up(inc, off);
            if (lane >= off) inc += v;
        }
        if (t < RADIX && lane == 63) S.wsum[wid] = inc;
        __syncthreads();
        if (t < RADIX) {
            unsigned wb = 0;
#pragma unroll
            for (int w = 0; w < 4; ++w) wb += (w < wid) ? S.wsum[w] : 0u;
            S.lscan[t] = wb + inc - c0;
            S.gbase[t] = c0 ? atomicAdd(&g0[t], c0) : 0u;
        }
    }
    __syncthreads();
#pragma unroll
    for (int c = 0; c < 4; ++c)
        if (dg[c] != 0xFFFFFFFFu)
            S.stage[S.lscan[dg[c]] + rk[c]] = pay[c];
    __syncthreads();
#pragma unroll
    for (int j = 0; j < 4; ++j) {
        int s = j * 512 + t;
        if (s < n) {
            uint4 v = S.stage[s];
            unsigned d = seg_of_wy(v.y);
            unsigned pos = S.gbase[d] + ((unsigned)s - S.lscan[d]);
            outp[pos] = v;
        }
    }
}

// ---------------- pass 2: per-segment (z,x97) scatter, 1024 threads ----------------
__global__ __launch_bounds__(1024) void pass2b_kernel(
    const uint4* __restrict__ inp, const unsigned* __restrict__ segBase,
    uint4* __restrict__ outp, int P)
{
    __shared__ unsigned bh[RADIX];
    __shared__ unsigned cur[RADIX];
    __shared__ unsigned lz[RADIX];
    __shared__ unsigned lsc[RADIX];
    __shared__ unsigned wsum[4];
    __shared__ uint4 stage[SEG_TILE];   // 32 KB

    int b = blockIdx.x;
    unsigned s0 = segBase[b];
    unsigned s1 = (b == RADIX - 1) ? (unsigned)P : segBase[b + 1];
    int t = threadIdx.x, lane = t & 63, wid = t >> 6;

    if (t < RADIX) bh[t] = 0;
    __syncthreads();

    // sweep 1: full-segment bin histogram (16 waves)
    for (unsigned i = s0 + t; i < s1; i += 1024)
        atomicAdd(&bh[b8_of_wy(inp[i].y)], 1u);
    __syncthreads();

    // exclusive scan of 256 bins -> global cursors
    {
        unsigned c0 = (t < RADIX) ? bh[t] : 0u;
        unsigned inc = c0;
#pragma unroll
        for (int off = 1; off < 64; off <<= 1) {
            unsigned v = __shfl_up(inc, off);
            if (lane >= off) inc += v;
        }
        if (t < RADIX && lane == 63) wsum[wid] = inc;
        __syncthreads();
        if (t < RADIX) {
            unsigned wb = 0;
#pragma unroll
            for (int w = 0; w < 4; ++w) wb += (w < wid) ? wsum[w] : 0u;
            cur[t] = s0 + wb + inc - c0;
        }
    }
    __syncthreads();

    // sweep 2: tiles -> LDS reorder -> coalesced chunked write-out
    for (unsigned tb = s0; tb < s1; tb += SEG_TILE) {
        unsigned m = min((unsigned)SEG_TILE, s1 - tb);
        if (t < RADIX) lz[t] = 0;
        __syncthreads();
        uint4 pay[2];
        unsigned rk[2], zz[2];
#pragma unroll
        for (int j = 0; j < 2; ++j) {
            int s = j * 1024 + t;
            if (s < (int)m) {
                uint4 v = inp[tb + (unsigned)s];
                pay[j] = v;
                zz[j] = b8_of_wy(v.y);
                rk[j] = atomicAdd(&lz[zz[j]], 1u);
            } else {
                zz[j] = 0xFFFFFFFFu;
            }
        }
        __syncthreads();
        {
            unsigned c0 = (t < RADIX) ? lz[t] : 0u;
            unsigned inc = c0;
#pragma unroll
            for (int off = 1; off < 64; off <<= 1) {
                unsigned v = __shfl_up(inc, off);
                if (lane >= off) inc += v;
            }
            if (t < RADIX && lane == 63) wsum[wid] = inc;
            __syncthreads();
            if (t < RADIX) {
                unsigned wb = 0;
#pragma unroll
                for (int w = 0; w < 4; ++w) wb += (w < wid) ? wsum[w] : 0u;
                lsc[t] = wb + inc - c0;
            }
        }
        __syncthreads();
#pragma unroll
        for (int j = 0; j < 2; ++j)
            if (zz[j] != 0xFFFFFFFFu)
                stage[lsc[zz[j]] + rk[j]] = pay[j];
        __syncthreads();
#pragma unroll
        for (int j = 0; j < 2; ++j) {
            int s = j * 1024 + t;
            if (s < (int)m) {
                uint4 v = stage[s];
                unsigned d = b8_of_wy(v.y);
                outp[cur[d] + ((unsigned)s - lsc[d])] = v;
            }
        }
        __syncthreads();
        if (t < RADIX) cur[t] += lz[t];
        __syncthreads();
    }
}

// ---------------- KNN main kernel (R6/R10-proven gather body) ----------------
__device__ __forceinline__ int swizzle_block(int b, int nb) {
    if ((nb & 7) == 0) {
        int per = nb >> 3;
        return (b & 7) * per + (b >> 3);
    }
    return b;
}

__device__ __forceinline__ void bev_knn_body(
    const float* __restrict__ pr, const int* __restrict__ pa,
    float u, int x, int y, int z, int oidx, int* __restrict__ out)
{
    float dist[K3];
#pragma unroll
    for (int k = 0; k < K3; ++k) {
        const int dz = k / 9 - 1;
        const int dy = (k / 3) % 3 - 1;
        const int dx = k % 3 - 1;
        int zz = z + dz, yy = y + dy, xx = x + dx;
        bool ok = ((unsigned)zz < (unsigned)DIM_D) &
                  ((unsigned)yy < (unsigned)DIM_H) &
                  ((unsigned)xx < (unsigned)DIM_W);
        int zi = ok ? zz : 0;
        int yi = ok ? yy : 0;
        int xi = ok ? xx : 0;
        float r = pr[((size_t)zi * DIM_H + yi) * DIM_W + xi];
        r = ok ? r : 0.0f;
        r = (r < 0.0f) ? INFINITY : r;
        float d = fabsf(r - u);
        dist[k] = (k == CENTER) ? 0.0f : d;
    }

    float bd[KNN];
    int   bk[KNN];
#pragma unroll
    for (int j = 0; j < KNN; ++j) { bd[j] = INFINITY; bk[j] = -1; }
#pragma unroll
    for (int k = 0; k < K3; ++k) {
        float dcur = dist[k];
        int   kcur = k;
#pragma unroll
        for (int j = 0; j < KNN; ++j) {
            bool take = dcur < bd[j];
            float td = bd[j]; int tk = bk[j];
            bd[j] = take ? dcur : bd[j];
            bk[j] = take ? kcur : bk[j];
            dcur  = take ? td : dcur;
            kcur  = take ? tk : kcur;
        }
    }

    int votes[KNN];
#pragma unroll
    for (int j = 0; j < KNN; ++j) {
        int k = bk[j];
        const int dz = k / 9 - 1;
        const int dy = (k / 3) % 3 - 1;
        const int dx = k % 3 - 1;
        int zz = z + dz, yy = y + dy, xx = x + dx;
        bool ok = ((unsigned)zz < (unsigned)DIM_D) &
                  ((unsigned)yy < (unsigned)DIM_H) &
                  ((unsigned)xx < (unsigned)DIM_W);
        int zi = ok ? zz : 0;
        int yi = ok ? yy : 0;
        int xi = ok ? xx : 0;
        int cls = pa[((size_t)zi * DIM_H + yi) * DIM_W + xi];
        cls = ok ? cls : 0;
        cls = (bd[j] > 1.0f) ? NCLASSES : cls;
        votes[j] = cls;
    }

    int best_cnt = 0, best_cls = 1;
#pragma unroll
    for (int j = 0; j < KNN; ++j) {
        int v = votes[j];
        if (v >= 1 && v <= NCLASSES - 1) {
            int cnt = 0;
#pragma unroll
            for (int i = 0; i < KNN; ++i) cnt += (votes[i] == v) ? 1 : 0;
            if (cnt > best_cnt || (cnt == best_cnt && v < best_cls)) {
                best_cnt = cnt;
                best_cls = v;
            }
        }
    }
    out[oidx] = best_cls;
}

__global__ __launch_bounds__(256) void bev_knn_aos_kernel(
    const float* __restrict__ pr, const int* __restrict__ pa,
    const uint4* __restrict__ payload, int* __restrict__ out, int P)
{
    int lb = swizzle_block(blockIdx.x, gridDim.x);
    int p = lb * blockDim.x + threadIdx.x;
    if (p >= P) return;
    uint4 w = payload[p];
    float u = __uint_as_float(w.x);
    int x = (int)(w.y & 0x7FFu);
    int y = (int)((w.y >> 11) & 0x7Fu);
    int z = (int)((w.y >> 18) & 0x1Fu);
    bev_knn_body(pr, pa, u, x, y, z, (int)w.z, out);
}

// ---------------- direct fallback ----------------
__global__ __launch_bounds__(256) void bev_knn_direct_kernel(
    const float* __restrict__ pr, const int* __restrict__ pa,
    const float* __restrict__ ur, const int* __restrict__ px,
    const int* __restrict__ py, const int* __restrict__ pz,
    int* __restrict__ out, int P)
{
    int p = blockIdx.x * blockDim.x + threadIdx.x;
    if (p >= P) return;
    bev_knn_body(pr, pa, ur[p], px[p], py[p], pz[p], p, out);
}

extern "C" void kernel_launch(void* const* d_in, const int* in_sizes, int n_in,
                              void* d_out, int out_size, void* d_ws, size_t ws_size,
                              hipStream_t stream) {
    const float* pr = (const float*)d_in[0];
    const float* ur = (const float*)d_in[1];
    const int*   pa = (const int*)d_in[2];
    const int*   px = (const int*)d_in[3];
    const int*   py = (const int*)d_in[4];
    const int*   pz = (const int*)d_in[5];
    int* out = (int*)d_out;
    int P = in_sizes[1];
    int gridH = (P + 4095) / 4096;
    int gridB = (P + BIN_PTS - 1) / BIN_PTS;
    int gridD = (P + 255) / 256;

    size_t h_b   = (size_t)RADIX * 4;     // 1 KB cursors
    size_t hb_b  = (size_t)RADIX * 4;     // 1 KB pristine bases
    size_t p_off = (h_b + hb_b + 15) & ~(size_t)15;
    size_t pay_b = (size_t)P * 16;
    size_t need  = p_off + 2 * pay_b;

    if (ws_size >= need) {
        char* ws = (char*)d_ws;
        unsigned* h0cur  = (unsigned*)ws;
        unsigned* h0base = (unsigned*)(ws + h_b);
        uint4*    pay1   = (uint4*)(ws + p_off);
        uint4*    pay2   = (uint4*)(ws + p_off + pay_b);

        hipMemsetAsync(h0cur, 0, h_b, stream);
        hist0_kernel<<<gridH, 256, 0, stream>>>(px, py, h0cur, P);
        scan256_dup_kernel<<<1, 256, 0, stream>>>(h0cur, h0base);
        bin_pass1_kernel<<<gridB, 512, 0, stream>>>(ur, px, py, pz,
                                                    h0cur, pay1, P);
        pass2b_kernel<<<RADIX, 1024, 0, stream>>>(pay1, h0base, pay2, P);
        bev_knn_aos_kernel<<<gridD, 256, 0, stream>>>(pr, pa, pay2, out, P);
    } else {
        bev_knn_direct_kernel<<<gridD, 256, 0, stream>>>(pr, pa, ur, px, py,
                                                         pz, out, P);
    }
}

// Round 13
// 195.326 us; speedup vs baseline: 1.2603x; 1.0203x over previous
//
#include <hip/hip_runtime.h>
#include <hip/hip_bf16.h>
#include <math.h>

#define KNN 5
#define K3 27
#define CENTER 13
#define NCLASSES 21
#define DIM_D 32
#define DIM_H 128
#define DIM_W 2048

#define RADIX 256
#define BIN_PTS 2048
#define SEG_TILE 2048

// Sort plan (grouping-exact, deterministic):
//   pass 1 (512 thr): bin by seg = y<<1 | x>>10   (256 bins, global cursors)
//   pass 2 (1024 thr): one block per segment; bin by b8 = (z<<3)|(x>>7 & 7)
//   Final order: (y, x10, z, x9..7) — measured R10/R11: main FETCH 45 MB.

// 4B-aligned float4 for unaligned-row loads (gfx950: dword-aligned dwordx4 ok)
typedef float float4u __attribute__((ext_vector_type(4), aligned(4)));

__device__ __forceinline__ unsigned seg_of_xy(int x, int y) {
    return ((unsigned)y << 1) | ((unsigned)x >> 10);
}
__device__ __forceinline__ unsigned seg_of_wy(unsigned wy) {
    return (((wy >> 11) & 0x7Fu) << 1) | ((wy >> 10) & 1u);
}
__device__ __forceinline__ unsigned b8_of_wy(unsigned wy) {
    return (((wy >> 18) & 31u) << 3) | ((wy >> 7) & 7u);
}

// ---------------- seg histogram ----------------
__global__ __launch_bounds__(256) void hist0_kernel(
    const int* __restrict__ px, const int* __restrict__ py,
    unsigned* __restrict__ h0, int P)
{
    __shared__ unsigned lh0[RADIX];
    int t = threadIdx.x;
    lh0[t] = 0;
    __syncthreads();
    int base4 = blockIdx.x * 1024 + t;
#pragma unroll
    for (int g = 0; g < 4; ++g) {
        int i4 = base4 + g * 256;
        int i0 = i4 * 4;
        if (i0 + 3 < P) {
            int4 X = ((const int4*)px)[i4];
            int4 Y = ((const int4*)py)[i4];
            atomicAdd(&lh0[seg_of_xy(X.x, Y.x)], 1u);
            atomicAdd(&lh0[seg_of_xy(X.y, Y.y)], 1u);
            atomicAdd(&lh0[seg_of_xy(X.z, Y.z)], 1u);
            atomicAdd(&lh0[seg_of_xy(X.w, Y.w)], 1u);
        } else {
            for (int i = i0; i < P; ++i)
                atomicAdd(&lh0[seg_of_xy(px[i], py[i])], 1u);
        }
    }
    __syncthreads();
    if (lh0[t]) atomicAdd(&h0[t], lh0[t]);
}

// exclusive scan of 256 entries; result to BOTH h (pass-1 cursors) and hbase
__global__ __launch_bounds__(256) void scan256_dup_kernel(
    unsigned* __restrict__ h, unsigned* __restrict__ hbase)
{
    __shared__ unsigned ws[4];
    int t = threadIdx.x, lane = t & 63, wid = t >> 6;
    unsigned a = h[t], ia = a;
#pragma unroll
    for (int off = 1; off < 64; off <<= 1) {
        unsigned v = __shfl_up(ia, off);
        if (lane >= off) ia += v;
    }
    if (lane == 63) ws[wid] = ia;
    __syncthreads();
    unsigned b = 0;
#pragma unroll
    for (int w = 0; w < 4; ++w) b += (w < wid) ? ws[w] : 0u;
    unsigned excl = b + ia - a;
    h[t] = excl;
    hbase[t] = excl;
}

// ---------------- pass 1: bin by seg, 512 threads ----------------
struct BinShared {
    unsigned lh[RADIX];
    unsigned lscan[RADIX];
    unsigned gbase[RADIX];
    unsigned wsum[4];
    uint4 stage[BIN_PTS];   // 32 KB
};

__global__ __launch_bounds__(512) void bin_pass1_kernel(
    const float* __restrict__ ur, const int* __restrict__ px,
    const int* __restrict__ py, const int* __restrict__ pz,
    unsigned* __restrict__ g0, uint4* __restrict__ outp, int P)
{
    __shared__ BinShared S;
    int t = threadIdx.x, lane = t & 63, wid = t >> 6;
    int bstart = blockIdx.x * BIN_PTS;
    int n = min(BIN_PTS, P - bstart);
    if (t < RADIX) S.lh[t] = 0;
    __syncthreads();

    uint4 pay[4];
    unsigned rk[4], dg[4];
    {
        int i4 = (bstart >> 2) + t;
        int i0 = i4 * 4;
        if (i0 + 3 < P) {
            int4 X = ((const int4*)px)[i4];
            int4 Y = ((const int4*)py)[i4];
            int4 Z = ((const int4*)pz)[i4];
            float4 U = ((const float4*)ur)[i4];
            int xs[4] = {X.x, X.y, X.z, X.w};
            int ys[4] = {Y.x, Y.y, Y.z, Y.w};
            int zs[4] = {Z.x, Z.y, Z.z, Z.w};
            float us[4] = {U.x, U.y, U.z, U.w};
#pragma unroll
            for (int c = 0; c < 4; ++c) {
                dg[c] = seg_of_xy(xs[c], ys[c]);
                rk[c] = atomicAdd(&S.lh[dg[c]], 1u);
                pay[c] = make_uint4(__float_as_uint(us[c]),
                    (unsigned)xs[c] | ((unsigned)ys[c] << 11) | ((unsigned)zs[c] << 18),
                    (unsigned)(i0 + c), 0u);
            }
        } else {
#pragma unroll
            for (int c = 0; c < 4; ++c) {
                int gi = i0 + c;
                if (gi < P) {
                    int x = px[gi], y = py[gi], z = pz[gi];
                    dg[c] = seg_of_xy(x, y);
                    rk[c] = atomicAdd(&S.lh[dg[c]], 1u);
                    pay[c] = make_uint4(__float_as_uint(ur[gi]),
                        (unsigned)x | ((unsigned)y << 11) | ((unsigned)z << 18),
                        (unsigned)gi, 0u);
                } else {
                    dg[c] = 0xFFFFFFFFu;
                }
            }
        }
    }
    __syncthreads();

    {
        unsigned c0 = (t < RADIX) ? S.lh[t] : 0u;
        unsigned inc = c0;
#pragma unroll
        for (int off = 1; off < 64; off <<= 1) {
            unsigned v = __shfl_up(inc, off);
            if (lane >= off) inc += v;
        }
        if (t < RADIX && lane == 63) S.wsum[wid] = inc;
        __syncthreads();
        if (t < RADIX) {
            unsigned wb = 0;
#pragma unroll
            for (int w = 0; w < 4; ++w) wb += (w < wid) ? S.wsum[w] : 0u;
            S.lscan[t] = wb + inc - c0;
            S.gbase[t] = c0 ? atomicAdd(&g0[t], c0) : 0u;
        }
    }
    __syncthreads();
#pragma unroll
    for (int c = 0; c < 4; ++c)
        if (dg[c] != 0xFFFFFFFFu)
            S.stage[S.lscan[dg[c]] + rk[c]] = pay[c];
    __syncthreads();
#pragma unroll
    for (int j = 0; j < 4; ++j) {
        int s = j * 512 + t;
        if (s < n) {
            uint4 v = S.stage[s];
            unsigned d = seg_of_wy(v.y);
            unsigned pos = S.gbase[d] + ((unsigned)s - S.lscan[d]);
            outp[pos] = v;
        }
    }
}

// ---------------- pass 2: per-segment (z,x97) scatter, 1024 threads ----------------
__global__ __launch_bounds__(1024) void pass2b_kernel(
    const uint4* __restrict__ inp, const unsigned* __restrict__ segBase,
    uint4* __restrict__ outp, int P)
{
    __shared__ unsigned bh[RADIX];
    __shared__ unsigned cur[RADIX];
    __shared__ unsigned lz[RADIX];
    __shared__ unsigned lsc[RADIX];
    __shared__ unsigned wsum[4];
    __shared__ uint4 stage[SEG_TILE];   // 32 KB

    int b = blockIdx.x;
    unsigned s0 = segBase[b];
    unsigned s1 = (b == RADIX - 1) ? (unsigned)P : segBase[b + 1];
    int t = threadIdx.x, lane = t & 63, wid = t >> 6;

    if (t < RADIX) bh[t] = 0;
    __syncthreads();

    for (unsigned i = s0 + t; i < s1; i += 1024)
        atomicAdd(&bh[b8_of_wy(inp[i].y)], 1u);
    __syncthreads();

    {
        unsigned c0 = (t < RADIX) ? bh[t] : 0u;
        unsigned inc = c0;
#pragma unroll
        for (int off = 1; off < 64; off <<= 1) {
            unsigned v = __shfl_up(inc, off);
            if (lane >= off) inc += v;
        }
        if (t < RADIX && lane == 63) wsum[wid] = inc;
        __syncthreads();
        if (t < RADIX) {
            unsigned wb = 0;
#pragma unroll
            for (int w = 0; w < 4; ++w) wb += (w < wid) ? wsum[w] : 0u;
            cur[t] = s0 + wb + inc - c0;
        }
    }
    __syncthreads();

    for (unsigned tb = s0; tb < s1; tb += SEG_TILE) {
        unsigned m = min((unsigned)SEG_TILE, s1 - tb);
        if (t < RADIX) lz[t] = 0;
        __syncthreads();
        uint4 pay[2];
        unsigned rk[2], zz[2];
#pragma unroll
        for (int j = 0; j < 2; ++j) {
            int s = j * 1024 + t;
            if (s < (int)m) {
                uint4 v = inp[tb + (unsigned)s];
                pay[j] = v;
                zz[j] = b8_of_wy(v.y);
                rk[j] = atomicAdd(&lz[zz[j]], 1u);
            } else {
                zz[j] = 0xFFFFFFFFu;
            }
        }
        __syncthreads();
        {
            unsigned c0 = (t < RADIX) ? lz[t] : 0u;
            unsigned inc = c0;
#pragma unroll
            for (int off = 1; off < 64; off <<= 1) {
                unsigned v = __shfl_up(inc, off);
                if (lane >= off) inc += v;
            }
            if (t < RADIX && lane == 63) wsum[wid] = inc;
            __syncthreads();
            if (t < RADIX) {
                unsigned wb = 0;
#pragma unroll
                for (int w = 0; w < 4; ++w) wb += (w < wid) ? wsum[w] : 0u;
                lsc[t] = wb + inc - c0;
            }
        }
        __syncthreads();
#pragma unroll
        for (int j = 0; j < 2; ++j)
            if (zz[j] != 0xFFFFFFFFu)
                stage[lsc[zz[j]] + rk[j]] = pay[j];
        __syncthreads();
#pragma unroll
        for (int j = 0; j < 2; ++j) {
            int s = j * 1024 + t;
            if (s < (int)m) {
                uint4 v = stage[s];
                unsigned d = b8_of_wy(v.y);
                outp[cur[d] + ((unsigned)s - lsc[d])] = v;
            }
        }
        __syncthreads();
        if (t < RADIX) cur[t] += lz[t];
        __syncthreads();
    }
}

// ---------------- KNN body: row-vectorized dwordx4 gathers ----------------
__device__ __forceinline__ void bev_knn_body(
    const float* __restrict__ pr, const int* __restrict__ pa,
    float u, int x, int y, int z, int oidx, int* __restrict__ out)
{
    // One 4B-aligned float4 load per (dz,dy) row covers x-1..x+2.
    // xo clamped so the 16B stays inside the row; s remaps loaded lanes:
    //   needed val_j = L[s+j], j=0..2, with L[-1]=L[4]=0 (zero padding).
    int xo = min(max(x - 1, 0), DIM_W - 4);
    int s = x - 1 - xo;             // -1 (x=0), 0 (common), 1 (x=2046), 2 (x=2047)

    float dist[K3];
#pragma unroll
    for (int r = 0; r < 9; ++r) {
        const int dz = r / 3 - 1;
        const int dy = r % 3 - 1;
        int zz = z + dz, yy = y + dy;
        bool ok = ((unsigned)zz < (unsigned)DIM_D) &
                  ((unsigned)yy < (unsigned)DIM_H);
        int row = ok ? (zz * DIM_H + yy) : 0;
        float4u l = *(const float4u*)(pr + (((size_t)row) << 11) + xo);
        float a0 = ok ? l.x : 0.f;
        float a1 = ok ? l.y : 0.f;
        float a2 = ok ? l.z : 0.f;
        float a3 = ok ? l.w : 0.f;
        // v_j = L[s+j]
        float v0 = (s == 0) ? a0 : ((s == -1) ? 0.f : ((s == 1) ? a1 : a2));
        float v1 = (s == 0) ? a1 : ((s == -1) ? a0 : ((s == 1) ? a2 : a3));
        float v2 = (s == 0) ? a2 : ((s == -1) ? a1 : ((s == 1) ? a3 : 0.f));
        v0 = (v0 < 0.f) ? INFINITY : v0;
        v1 = (v1 < 0.f) ? INFINITY : v1;
        v2 = (v2 < 0.f) ? INFINITY : v2;
        int k = r * 3;
        dist[k + 0] = fabsf(v0 - u);
        dist[k + 1] = (k + 1 == CENTER) ? 0.0f : fabsf(v1 - u);
        dist[k + 2] = fabsf(v2 - u);
    }

    // top-5 smallest, ties -> lower flat index (lax.top_k semantics)
    float bd[KNN];
    int   bk[KNN];
#pragma unroll
    for (int j = 0; j < KNN; ++j) { bd[j] = INFINITY; bk[j] = -1; }
#pragma unroll
    for (int k = 0; k < K3; ++k) {
        float dcur = dist[k];
        int   kcur = k;
#pragma unroll
        for (int j = 0; j < KNN; ++j) {
            bool take = dcur < bd[j];
            float td = bd[j]; int tk = bk[j];
            bd[j] = take ? dcur : bd[j];
            bk[j] = take ? kcur : bk[j];
            dcur  = take ? td : dcur;
            kcur  = take ? tk : kcur;
        }
    }

    // class gather only for the 5 winners; apply cutoff
    int votes[KNN];
#pragma unroll
    for (int j = 0; j < KNN; ++j) {
        int k = bk[j];
        const int dz = k / 9 - 1;
        const int dy = (k / 3) % 3 - 1;
        const int dx = k % 3 - 1;
        int zz = z + dz, yy = y + dy, xx = x + dx;
        bool ok = ((unsigned)zz < (unsigned)DIM_D) &
                  ((unsigned)yy < (unsigned)DIM_H) &
                  ((unsigned)xx < (unsigned)DIM_W);
        int zi = ok ? zz : 0;
        int yi = ok ? yy : 0;
        int xi = ok ? xx : 0;
        int cls = pa[((size_t)zi * DIM_H + yi) * DIM_W + xi];
        cls = ok ? cls : 0;
        cls = (bd[j] > 1.0f) ? NCLASSES : cls;
        votes[j] = cls;
    }

    int best_cnt = 0, best_cls = 1;
#pragma unroll
    for (int j = 0; j < KNN; ++j) {
        int v = votes[j];
        if (v >= 1 && v <= NCLASSES - 1) {
            int cnt = 0;
#pragma unroll
            for (int i = 0; i < KNN; ++i) cnt += (votes[i] == v) ? 1 : 0;
            if (cnt > best_cnt || (cnt == best_cnt && v < best_cls)) {
                best_cnt = cnt;
                best_cls = v;
            }
        }
    }
    out[oidx] = best_cls;
}

__device__ __forceinline__ int swizzle_block(int b, int nb) {
    if ((nb & 7) == 0) {
        int per = nb >> 3;
        return (b & 7) * per + (b >> 3);
    }
    return b;
}

__global__ __launch_bounds__(256) void bev_knn_aos_kernel(
    const float* __restrict__ pr, const int* __restrict__ pa,
    const uint4* __restrict__ payload, int* __restrict__ out, int P)
{
    int lb = swizzle_block(blockIdx.x, gridDim.x);
    int p = lb * blockDim.x + threadIdx.x;
    if (p >= P) return;
    uint4 w = payload[p];
    float u = __uint_as_float(w.x);
    int x = (int)(w.y & 0x7FFu);
    int y = (int)((w.y >> 11) & 0x7Fu);
    int z = (int)((w.y >> 18) & 0x1Fu);
    bev_knn_body(pr, pa, u, x, y, z, (int)w.z, out);
}

__global__ __launch_bounds__(256) void bev_knn_direct_kernel(
    const float* __restrict__ pr, const int* __restrict__ pa,
    const float* __restrict__ ur, const int* __restrict__ px,
    const int* __restrict__ py, const int* __restrict__ pz,
    int* __restrict__ out, int P)
{
    int p = blockIdx.x * blockDim.x + threadIdx.x;
    if (p >= P) return;
    bev_knn_body(pr, pa, ur[p], px[p], py[p], pz[p], p, out);
}

extern "C" void kernel_launch(void* const* d_in, const int* in_sizes, int n_in,
                              void* d_out, int out_size, void* d_ws, size_t ws_size,
                              hipStream_t stream) {
    const float* pr = (const float*)d_in[0];
    const float* ur = (const float*)d_in[1];
    const int*   pa = (const int*)d_in[2];
    const int*   px = (const int*)d_in[3];
    const int*   py = (const int*)d_in[4];
    const int*   pz = (const int*)d_in[5];
    int* out = (int*)d_out;
    int P = in_sizes[1];
    int gridH = (P + 4095) / 4096;
    int gridB = (P + BIN_PTS - 1) / BIN_PTS;
    int gridD = (P + 255) / 256;

    size_t h_b   = (size_t)RADIX * 4;
    size_t hb_b  = (size_t)RADIX * 4;
    size_t p_off = (h_b + hb_b + 15) & ~(size_t)15;
    size_t pay_b = (size_t)P * 16;
    size_t need  = p_off + 2 * pay_b;

    if (ws_size >= need) {
        char* ws = (char*)d_ws;
        unsigned* h0cur  = (unsigned*)ws;
        unsigned* h0base = (unsigned*)(ws + h_b);
        uint4*    pay1   = (uint4*)(ws + p_off);
        uint4*    pay2   = (uint4*)(ws + p_off + pay_b);

        hipMemsetAsync(h0cur, 0, h_b, stream);
        hist0_kernel<<<gridH, 256, 0, stream>>>(px, py, h0cur, P);
        scan256_dup_kernel<<<1, 256, 0, stream>>>(h0cur, h0base);
        bin_pass1_kernel<<<gridB, 512, 0, stream>>>(ur, px, py, pz,
                                                    h0cur, pay1, P);
        pass2b_kernel<<<RADIX, 1024, 0, stream>>>(pay1, h0base, pay2, P);
        bev_knn_aos_kernel<<<gridD, 256, 0, stream>>>(pr, pa, pay2, out, P);
    } else {
        bev_knn_direct_kernel<<<gridD, 256, 0, stream>>>(pr, pa, ur, px, py,
                                                         pz, out, P);
    }
}